// Round 1
// baseline (1029.658 us; speedup 1.0000x reference)
//
#include <hip/hip_runtime.h>

// Problem dims (fixed by reference)
#define BB 2
#define CC 2
#define DD 96
#define HH 192
#define WW 192
static constexpr long NV   = (long)BB * DD * HH * WW;   // 7,077,888 voxels
static constexpr int  HW_  = HH * WW;                   // 36,864
static constexpr long DHW_ = (long)DD * HW_;            // 3,538,944

// ---------------------------------------------------------------------------
// K1: sliding window sums along W (k=3,5,7), zero-padded.
// Pack per voxel into uint16: bit0 = label, bits1-2 = s3 (0..3),
// bits3-5 = s5 (0..5), bits6-8 = s7 (0..7).
// ---------------------------------------------------------------------------
__global__ __launch_bounds__(256) void k_xsum(const int* __restrict__ lab,
                                              unsigned short* __restrict__ xs) {
    long i = (long)blockIdx.x * blockDim.x + threadIdx.x;
    if (i >= NV) return;
    int  w   = (int)(i % WW);
    long row = i - w;
    int v[7];
#pragma unroll
    for (int t = 0; t < 7; ++t) {
        int ww = w + t - 3;
        v[t] = (ww >= 0 && ww < WW) ? lab[row + ww] : 0;
    }
    int s7 = v[0] + v[1] + v[2] + v[3] + v[4] + v[5] + v[6];
    int s5 = s7 - v[0] - v[6];
    int s3 = s5 - v[1] - v[5];
    xs[i] = (unsigned short)(v[3] | (s3 << 1) | (s5 << 3) | (s7 << 6));
}

// ---------------------------------------------------------------------------
// K2: sliding window sums along H. Input packed xs, output packed ys:
// bit0 = label, bits1-4 = t3 (0..9), bits5-9 = t5 (0..25), bits10-15 = t7 (0..49)
// ---------------------------------------------------------------------------
__global__ __launch_bounds__(256) void k_ysum(const unsigned short* __restrict__ xs,
                                              unsigned short* __restrict__ ys) {
    long i = (long)blockIdx.x * blockDim.x + threadIdx.x;
    if (i >= NV) return;
    int  w = (int)(i % WW);
    long r = i / WW;
    int  h = (int)(r % HH);
    long col0 = i - (long)h * WW;   // (b,d,0,w)
    unsigned v[7];
#pragma unroll
    for (int t = 0; t < 7; ++t) {
        int hh = h + t - 3;
        v[t] = (hh >= 0 && hh < HH) ? (unsigned)xs[col0 + (long)hh * WW] : 0u;
    }
    unsigned t3 = ((v[2] >> 1) & 3u) + ((v[3] >> 1) & 3u) + ((v[4] >> 1) & 3u);
    unsigned t5 = ((v[1] >> 3) & 7u) + ((v[2] >> 3) & 7u) + ((v[3] >> 3) & 7u)
                + ((v[4] >> 3) & 7u) + ((v[5] >> 3) & 7u);
    unsigned t7 = ((v[0] >> 6) & 7u) + ((v[1] >> 6) & 7u) + ((v[2] >> 6) & 7u)
                + ((v[3] >> 6) & 7u) + ((v[4] >> 6) & 7u) + ((v[5] >> 6) & 7u)
                + ((v[6] >> 6) & 7u);
    ys[i] = (unsigned short)((v[3] & 1u) | (t3 << 1) | (t5 << 5) | (t7 << 10));
}

// ---------------------------------------------------------------------------
// K3: sliding window along D -> full 3D sums S3,S5,S7; analytic in-bounds
// count; boundary weight wm; NLL from logits (C=2 log-softmax).
// Block-reduce Σnll, Σ(nll·wm), max(wm) -> global atomics.
// ---------------------------------------------------------------------------
__device__ __forceinline__ int axcnt(int x, int r, int N) {
    int lo = x - r; if (lo < 0) lo = 0;
    int hi = x + r; if (hi > N - 1) hi = N - 1;
    return hi - lo + 1;
}

__global__ __launch_bounds__(256) void k_loss(const unsigned short* __restrict__ ys,
                                              const float* __restrict__ logits,
                                              double* __restrict__ acc,
                                              unsigned* __restrict__ wmaxb) {
    long i = (long)blockIdx.x * blockDim.x + threadIdx.x;
    float nll = 0.f, nw = 0.f, wm = 0.f;
    if (i < NV) {
        int  w  = (int)(i % WW);
        long r  = i / WW;
        int  h  = (int)(r % HH);
        long r2 = r / HH;
        int  d  = (int)(r2 % DD);
        int  b  = (int)(r2 / DD);

        long base = (long)b * DD * HW_ + (long)h * WW + w;  // (b,0,h,w)
        unsigned v[7];
#pragma unroll
        for (int t = 0; t < 7; ++t) {
            int dd = d + t - 3;
            v[t] = (dd >= 0 && dd < DD) ? (unsigned)ys[base + (long)dd * HW_] : 0u;
        }
        int lab = (int)(v[3] & 1u);
        int S3 = (int)(((v[2] >> 1) & 15u) + ((v[3] >> 1) & 15u) + ((v[4] >> 1) & 15u));
        int S5 = (int)(((v[1] >> 5) & 31u) + ((v[2] >> 5) & 31u) + ((v[3] >> 5) & 31u)
                     + ((v[4] >> 5) & 31u) + ((v[5] >> 5) & 31u));
        int S7 = (int)((v[0] >> 10) + (v[1] >> 10) + (v[2] >> 10) + (v[3] >> 10)
                     + (v[4] >> 10) + (v[5] >> 10) + (v[6] >> 10));

        float fl = (float)lab;
        // k = 3
        {
            int  c   = axcnt(w, 1, WW) * axcnt(h, 1, HH) * axcnt(d, 1, DD);
            float inv = 1.0f / 27.0f;
            wm += fabsf(fl - (float)S3 * inv) + fabsf((1.0f - fl) - (float)(c - S3) * inv);
        }
        // k = 5
        {
            int  c   = axcnt(w, 2, WW) * axcnt(h, 2, HH) * axcnt(d, 2, DD);
            float inv = 1.0f / 125.0f;
            wm += fabsf(fl - (float)S5 * inv) + fabsf((1.0f - fl) - (float)(c - S5) * inv);
        }
        // k = 7
        {
            int  c   = axcnt(w, 3, WW) * axcnt(h, 3, HH) * axcnt(d, 3, DD);
            float inv = 1.0f / 343.0f;
            wm += fabsf(fl - (float)S7 * inv) + fabsf((1.0f - fl) - (float)(c - S7) * inv);
        }

        // NLL: log-softmax over C=2
        long li = (long)b * CC * DHW_ + (long)d * HW_ + (long)h * WW + w;  // c = 0
        float l0 = logits[li];
        float l1 = logits[li + DHW_];
        float m  = fmaxf(l0, l1);
        float lse = m + logf(expf(l0 - m) + expf(l1 - m));
        nll = lse - (lab ? l1 : l0);
        nw  = nll * wm;
    }

    // wave (64-lane) reduction
#pragma unroll
    for (int off = 32; off > 0; off >>= 1) {
        nll += __shfl_down(nll, off);
        nw  += __shfl_down(nw, off);
        wm   = fmaxf(wm, __shfl_down(wm, off));
    }
    __shared__ float s_nll[4], s_nw[4], s_wm[4];
    int wid  = threadIdx.x >> 6;
    int lane = threadIdx.x & 63;
    if (lane == 0) { s_nll[wid] = nll; s_nw[wid] = nw; s_wm[wid] = wm; }
    __syncthreads();
    if (threadIdx.x == 0) {
        float a = 0.f, p = 0.f, mx = 0.f;
#pragma unroll
        for (int t = 0; t < 4; ++t) {
            a += s_nll[t]; p += s_nw[t]; mx = fmaxf(mx, s_wm[t]);
        }
        atomicAdd(&acc[0], (double)a);
        atomicAdd(&acc[1], (double)p);
        atomicMax(wmaxb, __float_as_uint(mx));   // wm >= 0 -> uint-ordered
    }
}

// ---------------------------------------------------------------------------
// K4: finalize scalar loss
// ---------------------------------------------------------------------------
__global__ void k_fin(const double* __restrict__ acc,
                      const unsigned* __restrict__ wmaxb,
                      float* __restrict__ out) {
    if (threadIdx.x == 0 && blockIdx.x == 0) {
        float  wmax = __uint_as_float(*wmaxb);
        double s = acc[0], p = acc[1];
        double res = (wmax > 0.f) ? (s + 2.0 * p / (double)wmax) : (s + 2.0 * p);
        out[0] = (float)(res / (double)NV);
    }
}

extern "C" void kernel_launch(void* const* d_in, const int* in_sizes, int n_in,
                              void* d_out, int out_size, void* d_ws, size_t ws_size,
                              hipStream_t stream) {
    const float* logits = (const float*)d_in[0];
    const int*   labels = (const int*)d_in[1];
    float*       out    = (float*)d_out;

    char* ws = (char*)d_ws;
    double*   acc   = (double*)ws;              // 16 B: sum_nll, sum_nll*wm
    unsigned* wmaxb = (unsigned*)(ws + 16);     // 4 B: max(wm) as float bits
    unsigned short* xs = (unsigned short*)(ws + 256);
    unsigned short* ys = xs + NV;
    // total ws use: 256 + 2 * NV * 2 bytes ~= 28.3 MB

    hipMemsetAsync(ws, 0, 256, stream);         // zero accumulators each call

    const int  threads = 256;
    const long blocks  = (NV + threads - 1) / threads;  // 27,648

    k_xsum<<<(unsigned)blocks, threads, 0, stream>>>(labels, xs);
    k_ysum<<<(unsigned)blocks, threads, 0, stream>>>(xs, ys);
    k_loss<<<(unsigned)blocks, threads, 0, stream>>>(ys, logits, acc, wmaxb);
    k_fin<<<1, 64, 0, stream>>>(acc, wmaxb, out);
}

// Round 2
// 87.237 us; speedup vs baseline: 11.8030x; 11.8030x over previous
//
#include <hip/hip_runtime.h>

// Problem dims (fixed by reference)
#define BB 2
#define CC 2
#define DD 96
#define HH 192
#define WW 192
static constexpr int NV   = BB * DD * HH * WW;   // 7,077,888 voxels
static constexpr int HW_  = HH * WW;             // 36,864
static constexpr int DHW_ = DD * HW_;            // 3,538,944

#define NBLK 2048   // k_loss grid: atomic-free two-stage reduction

// ---------------------------------------------------------------------------
// K1: sliding window sums along W (k=3,5,7), zero-padded.
// Pack per voxel into uint16: bit0 = label, bits1-2 = s3, bits3-5 = s5,
// bits6-8 = s7.
// ---------------------------------------------------------------------------
__global__ __launch_bounds__(256) void k_xsum(const int* __restrict__ lab,
                                              unsigned short* __restrict__ xs) {
    int i = blockIdx.x * 256 + threadIdx.x;
    if (i >= NV) return;
    int w   = i % WW;
    int row = i - w;
    int v[7];
#pragma unroll
    for (int t = 0; t < 7; ++t) {
        int ww = w + t - 3;
        v[t] = (ww >= 0 && ww < WW) ? lab[row + ww] : 0;
    }
    int s7 = v[0] + v[1] + v[2] + v[3] + v[4] + v[5] + v[6];
    int s5 = s7 - v[0] - v[6];
    int s3 = s5 - v[1] - v[5];
    xs[i] = (unsigned short)(v[3] | (s3 << 1) | (s5 << 3) | (s7 << 6));
}

// ---------------------------------------------------------------------------
// K2: sliding window sums along H. Output packed ys:
// bit0 = label, bits1-4 = t3, bits5-9 = t5, bits10-15 = t7.
// ---------------------------------------------------------------------------
__global__ __launch_bounds__(256) void k_ysum(const unsigned short* __restrict__ xs,
                                              unsigned short* __restrict__ ys) {
    int i = blockIdx.x * 256 + threadIdx.x;
    if (i >= NV) return;
    int h = (i / WW) % HH;
    unsigned v[7];
#pragma unroll
    for (int t = 0; t < 7; ++t) {
        int hh = h + t - 3;
        v[t] = (hh >= 0 && hh < HH) ? (unsigned)xs[i + (t - 3) * WW] : 0u;
    }
    unsigned t3 = ((v[2] >> 1) & 3u) + ((v[3] >> 1) & 3u) + ((v[4] >> 1) & 3u);
    unsigned t5 = ((v[1] >> 3) & 7u) + ((v[2] >> 3) & 7u) + ((v[3] >> 3) & 7u)
                + ((v[4] >> 3) & 7u) + ((v[5] >> 3) & 7u);
    unsigned t7 = ((v[0] >> 6) & 7u) + ((v[1] >> 6) & 7u) + ((v[2] >> 6) & 7u)
                + ((v[3] >> 6) & 7u) + ((v[4] >> 6) & 7u) + ((v[5] >> 6) & 7u)
                + ((v[6] >> 6) & 7u);
    ys[i] = (unsigned short)((v[3] & 1u) | (t3 << 1) | (t5 << 5) | (t7 << 10));
}

// ---------------------------------------------------------------------------
// K3: grid-stride over voxels; D-window -> S3,S5,S7; analytic border counts;
// wm; NLL (C=2 log-softmax). Per-block partials -> ws (NO atomics).
// ---------------------------------------------------------------------------
__device__ __forceinline__ int axcnt(int x, int r, int N) {
    int lo = x - r; if (lo < 0) lo = 0;
    int hi = x + r; if (hi > N - 1) hi = N - 1;
    return hi - lo + 1;
}

__global__ __launch_bounds__(256) void k_loss(const unsigned short* __restrict__ ys,
                                              const float* __restrict__ logits,
                                              float* __restrict__ p_nll,
                                              float* __restrict__ p_nw,
                                              float* __restrict__ p_wm) {
    float acc_n = 0.f, acc_p = 0.f, mx = 0.f;
    for (int i = blockIdx.x * 256 + threadIdx.x; i < NV; i += NBLK * 256) {
        int w  = i % WW;
        int r  = i / WW;
        int h  = r % HH;
        int r2 = r / HH;
        int d  = r2 % DD;
        int b  = r2 / DD;

        unsigned v[7];
#pragma unroll
        for (int t = 0; t < 7; ++t) {
            int dd = d + t - 3;
            v[t] = (dd >= 0 && dd < DD) ? (unsigned)ys[i + (t - 3) * HW_] : 0u;
        }
        int lab = (int)(v[3] & 1u);
        int S3 = (int)(((v[2] >> 1) & 15u) + ((v[3] >> 1) & 15u) + ((v[4] >> 1) & 15u));
        int S5 = (int)(((v[1] >> 5) & 31u) + ((v[2] >> 5) & 31u) + ((v[3] >> 5) & 31u)
                     + ((v[4] >> 5) & 31u) + ((v[5] >> 5) & 31u));
        int S7 = (int)((v[0] >> 10) + (v[1] >> 10) + (v[2] >> 10) + (v[3] >> 10)
                     + (v[4] >> 10) + (v[5] >> 10) + (v[6] >> 10));

        float fl = (float)lab;
        float wm = 0.f;
        {
            int c = axcnt(w, 1, WW) * axcnt(h, 1, HH) * axcnt(d, 1, DD);
            const float inv = 1.0f / 27.0f;
            wm += fabsf(fl - (float)S3 * inv) + fabsf((1.0f - fl) - (float)(c - S3) * inv);
        }
        {
            int c = axcnt(w, 2, WW) * axcnt(h, 2, HH) * axcnt(d, 2, DD);
            const float inv = 1.0f / 125.0f;
            wm += fabsf(fl - (float)S5 * inv) + fabsf((1.0f - fl) - (float)(c - S5) * inv);
        }
        {
            int c = axcnt(w, 3, WW) * axcnt(h, 3, HH) * axcnt(d, 3, DD);
            const float inv = 1.0f / 343.0f;
            wm += fabsf(fl - (float)S7 * inv) + fabsf((1.0f - fl) - (float)(c - S7) * inv);
        }

        // NLL over C=2: logits index for c=0 is i + b*DHW_ (layout identity)
        float l0 = logits[i + b * DHW_];
        float l1 = logits[i + b * DHW_ + DHW_];
        float m   = fmaxf(l0, l1);
        float lse = m + __logf(__expf(l0 - m) + __expf(l1 - m));
        float nll = lse - (lab ? l1 : l0);

        acc_n += nll;
        acc_p += nll * wm;
        mx = fmaxf(mx, wm);
    }

    // wave reduce
#pragma unroll
    for (int off = 32; off > 0; off >>= 1) {
        acc_n += __shfl_down(acc_n, off);
        acc_p += __shfl_down(acc_p, off);
        mx     = fmaxf(mx, __shfl_down(mx, off));
    }
    __shared__ float s_n[4], s_p[4], s_m[4];
    int wid  = threadIdx.x >> 6;
    int lane = threadIdx.x & 63;
    if (lane == 0) { s_n[wid] = acc_n; s_p[wid] = acc_p; s_m[wid] = mx; }
    __syncthreads();
    if (threadIdx.x == 0) {
        float a = 0.f, p = 0.f, m2 = 0.f;
#pragma unroll
        for (int t = 0; t < 4; ++t) { a += s_n[t]; p += s_p[t]; m2 = fmaxf(m2, s_m[t]); }
        p_nll[blockIdx.x] = a;
        p_nw[blockIdx.x]  = p;
        p_wm[blockIdx.x]  = m2;
    }
}

// ---------------------------------------------------------------------------
// K4: reduce NBLK partials -> scalar loss (single block)
// ---------------------------------------------------------------------------
__global__ __launch_bounds__(256) void k_fin(const float* __restrict__ pn,
                                             const float* __restrict__ pw,
                                             const float* __restrict__ pm,
                                             float* __restrict__ out) {
    double s = 0.0, p = 0.0;
    float mx = 0.f;
    for (int t = threadIdx.x; t < NBLK; t += 256) {
        s += (double)pn[t];
        p += (double)pw[t];
        mx = fmaxf(mx, pm[t]);
    }
#pragma unroll
    for (int off = 32; off > 0; off >>= 1) {
        s  += __shfl_down(s, off);
        p  += __shfl_down(p, off);
        mx  = fmaxf(mx, __shfl_down(mx, off));
    }
    __shared__ double sh_s[4], sh_p[4];
    __shared__ float  sh_m[4];
    int wid  = threadIdx.x >> 6;
    int lane = threadIdx.x & 63;
    if (lane == 0) { sh_s[wid] = s; sh_p[wid] = p; sh_m[wid] = mx; }
    __syncthreads();
    if (threadIdx.x == 0) {
        double S = 0.0, P = 0.0;
        float  M = 0.f;
#pragma unroll
        for (int t = 0; t < 4; ++t) { S += sh_s[t]; P += sh_p[t]; M = fmaxf(M, sh_m[t]); }
        double res = (M > 0.f) ? (S + 2.0 * P / (double)M) : S;
        out[0] = (float)(res / (double)NV);
    }
}

extern "C" void kernel_launch(void* const* d_in, const int* in_sizes, int n_in,
                              void* d_out, int out_size, void* d_ws, size_t ws_size,
                              hipStream_t stream) {
    const float* logits = (const float*)d_in[0];
    const int*   labels = (const int*)d_in[1];
    float*       out    = (float*)d_out;

    char* ws = (char*)d_ws;
    float* p_nll = (float*)ws;                    // NBLK floats
    float* p_nw  = (float*)(ws + 8192);           // NBLK floats
    float* p_wm  = (float*)(ws + 16384);          // NBLK floats
    unsigned short* xs = (unsigned short*)(ws + 32768);
    unsigned short* ys = xs + NV;
    // ws use: 32 KB + 2 * NV * 2 B ~= 28.3 MB. All partial slots are fully
    // rewritten every call -> no memset needed (deterministic).

    const int threads = 256;
    const int blocks  = (NV + threads - 1) / threads;  // 27,648

    k_xsum<<<blocks, threads, 0, stream>>>(labels, xs);
    k_ysum<<<blocks, threads, 0, stream>>>(xs, ys);
    k_loss<<<NBLK, threads, 0, stream>>>(ys, logits, p_nll, p_nw, p_wm);
    k_fin<<<1, threads, 0, stream>>>(p_nll, p_nw, p_wm, out);
}

// Round 3
// 51.978 us; speedup vs baseline: 19.8094x; 1.6783x over previous
//
#include <hip/hip_runtime.h>

// Problem dims (fixed by reference)
#define BB 2
#define CC 2
#define DD 96
#define HH 192
#define WW 192
static constexpr int NV   = BB * DD * HH * WW;   // 7,077,888 voxels
static constexpr int HW_  = HH * WW;             // 36,864
static constexpr int DHW_ = DD * HW_;            // 3,538,944
static constexpr int ROWS = BB * DD * HH;        // 36,864 W-rows
static constexpr int QPR  = WW / 4;              // 48 quads per row
static constexpr int RPB  = 4;                   // rows per block
static constexpr int TPB  = QPR * RPB;           // 192 threads
static constexpr int NBLKS = ROWS / RPB;         // 9,216 blocks

// packed-field masks (2 ushorts per uint32; sums stay within 16-bit lanes)
#define PM1 0x00010001u
#define PM3 0x00030003u
#define PM7 0x00070007u
#define PMF 0x000F000Fu
#define PM1F 0x001F001Fu
#define PM3F 0x003F003Fu

// ---------------------------------------------------------------------------
// K1: W-window sums (k=3,5,7) via rolling sums over 12 neighbors.
// 4 voxels/thread. Pack uint16: bit0=lab, b1-2=s3, b3-5=s5, b6-8=s7.
// ---------------------------------------------------------------------------
__global__ __launch_bounds__(TPB) void k_xsum(const int* __restrict__ lab,
                                              unsigned short* __restrict__ xs) {
    int t = threadIdx.x;
    int r = t / QPR;
    int q = t - r * QPR;
    int row = blockIdx.x * RPB + r;
    int i0  = row * WW + q * 4;            // element index, %4==0

    const int4* l4 = (const int4*)lab;
    int4 cur = l4[i0 >> 2];
    int4 prv = (q > 0)       ? l4[(i0 >> 2) - 1] : int4{0, 0, 0, 0};
    int4 nxt = (q < QPR - 1) ? l4[(i0 >> 2) + 1] : int4{0, 0, 0, 0};

    // v[0..11] = labels at w-4 .. w+7 (w = q*4)
    int v[12] = {prv.x, prv.y, prv.z, prv.w,
                 cur.x, cur.y, cur.z, cur.w,
                 nxt.x, nxt.y, nxt.z, nxt.w};

    int s7[4], s5[4], s3[4];
    s7[0] = v[1] + v[2] + v[3] + v[4] + v[5] + v[6] + v[7];
#pragma unroll
    for (int j = 0; j < 3; ++j) s7[j + 1] = s7[j] - v[j + 1] + v[j + 8];
#pragma unroll
    for (int j = 0; j < 4; ++j) {
        s5[j] = s7[j] - v[j + 1] - v[j + 7];
        s3[j] = s5[j] - v[j + 2] - v[j + 6];
    }
    unsigned short o[4];
#pragma unroll
    for (int j = 0; j < 4; ++j)
        o[j] = (unsigned short)(v[j + 4] | (s3[j] << 1) | (s5[j] << 3) | (s7[j] << 6));
    *(ushort2*)&o[0];  // no-op; store as uint2 below
    uint2 st;
    st.x = (unsigned)o[0] | ((unsigned)o[1] << 16);
    st.y = (unsigned)o[2] | ((unsigned)o[3] << 16);
    *(uint2*)(xs + i0) = st;
}

// ---------------------------------------------------------------------------
// K2: H-window sums, SWAR on packed uint32 (2 voxels/word), 4 voxels/thread.
// Output uint16: bit0=lab, b1-4=t3(<=9), b5-9=t5(<=25), b10-15=t7(<=49).
// ---------------------------------------------------------------------------
__device__ __forceinline__ unsigned ypack(const unsigned* g) {
    unsigned t3 = ((g[2] >> 1) & PM3) + ((g[3] >> 1) & PM3) + ((g[4] >> 1) & PM3);
    unsigned t5 = ((g[1] >> 3) & PM7) + ((g[2] >> 3) & PM7) + ((g[3] >> 3) & PM7)
                + ((g[4] >> 3) & PM7) + ((g[5] >> 3) & PM7);
    unsigned t7 = ((g[0] >> 6) & PM7) + ((g[1] >> 6) & PM7) + ((g[2] >> 6) & PM7)
                + ((g[3] >> 6) & PM7) + ((g[4] >> 6) & PM7) + ((g[5] >> 6) & PM7)
                + ((g[6] >> 6) & PM7);
    return (g[3] & PM1) | (t3 << 1) | (t5 << 5) | (t7 << 10);
}

__global__ __launch_bounds__(TPB) void k_ysum(const unsigned short* __restrict__ xs,
                                              unsigned short* __restrict__ ys) {
    int t = threadIdx.x;
    int r = t / QPR;
    int q = t - r * QPR;
    int row = blockIdx.x * RPB + r;
    int h   = row % HH;
    int i0  = row * WW + q * 4;

    unsigned gx[7], gy[7];
#pragma unroll
    for (int k = 0; k < 7; ++k) {
        int hh = h + k - 3;
        if (hh >= 0 && hh < HH) {
            uint2 u = *(const uint2*)(xs + i0 + (k - 3) * WW);
            gx[k] = u.x; gy[k] = u.y;
        } else { gx[k] = 0u; gy[k] = 0u; }
    }
    uint2 st;
    st.x = ypack(gx);
    st.y = ypack(gy);
    *(uint2*)(ys + i0) = st;
}

// ---------------------------------------------------------------------------
// K3: D-window (SWAR) -> S3,S5,S7; analytic counts; wm = 3 +/- q;
// nll = softplus(+/-(l0-l1)); block partials (no atomics).
// ---------------------------------------------------------------------------
__global__ __launch_bounds__(TPB) void k_loss(const unsigned short* __restrict__ ys,
                                              const float* __restrict__ logits,
                                              float* __restrict__ p_nll,
                                              float* __restrict__ p_nw,
                                              float* __restrict__ p_wm) {
    int t = threadIdx.x;
    int r = t / QPR;
    int q = t - r * QPR;
    int row = blockIdx.x * RPB + r;
    int h   = row % HH;
    int rd  = row / HH;
    int d   = rd % DD;
    int b   = rd / DD;
    int i0  = row * WW + q * 4;

    unsigned ux[7], uy[7];
#pragma unroll
    for (int k = 0; k < 7; ++k) {
        int dd = d + k - 3;          // block-uniform branch
        if (dd >= 0 && dd < DD) {
            uint2 u = *(const uint2*)(ys + i0 + (k - 3) * HW_);
            ux[k] = u.x; uy[k] = u.y;
        } else { ux[k] = 0u; uy[k] = 0u; }
    }
    // packed sums: per 16-bit lane, max 27 / 125 / 343 — no cross-lane carry
    unsigned S3x = ((ux[2] >> 1) & PMF) + ((ux[3] >> 1) & PMF) + ((ux[4] >> 1) & PMF);
    unsigned S3y = ((uy[2] >> 1) & PMF) + ((uy[3] >> 1) & PMF) + ((uy[4] >> 1) & PMF);
    unsigned S5x = ((ux[1] >> 5) & PM1F) + ((ux[2] >> 5) & PM1F) + ((ux[3] >> 5) & PM1F)
                 + ((ux[4] >> 5) & PM1F) + ((ux[5] >> 5) & PM1F);
    unsigned S5y = ((uy[1] >> 5) & PM1F) + ((uy[2] >> 5) & PM1F) + ((uy[3] >> 5) & PM1F)
                 + ((uy[4] >> 5) & PM1F) + ((uy[5] >> 5) & PM1F);
    unsigned S7x = ((ux[0] >> 10) & PM3F) + ((ux[1] >> 10) & PM3F) + ((ux[2] >> 10) & PM3F)
                 + ((ux[3] >> 10) & PM3F) + ((ux[4] >> 10) & PM3F) + ((ux[5] >> 10) & PM3F)
                 + ((ux[6] >> 10) & PM3F);
    unsigned S7y = ((uy[0] >> 10) & PM3F) + ((uy[1] >> 10) & PM3F) + ((uy[2] >> 10) & PM3F)
                 + ((uy[3] >> 10) & PM3F) + ((uy[4] >> 10) & PM3F) + ((uy[5] >> 10) & PM3F)
                 + ((uy[6] >> 10) & PM3F);

    // per-thread-uniform axis counts for h, d
    int ch3 = 1 + min(h, 1) + min(HH - 1 - h, 1);
    int ch5 = 1 + min(h, 2) + min(HH - 1 - h, 2);
    int ch7 = 1 + min(h, 3) + min(HH - 1 - h, 3);
    int cd3 = 1 + min(d, 1) + min(DD - 1 - d, 1);
    int cd5 = 1 + min(d, 2) + min(DD - 1 - d, 2);
    int cd7 = 1 + min(d, 3) + min(DD - 1 - d, 3);
    int chd3 = ch3 * cd3, chd5 = ch5 * cd5, chd7 = ch7 * cd7;

    const float4 L0 = *(const float4*)(logits + i0 + b * DHW_);
    const float4 L1 = *(const float4*)(logits + i0 + b * DHW_ + DHW_);
    float l0a[4] = {L0.x, L0.y, L0.z, L0.w};
    float l1a[4] = {L1.x, L1.y, L1.z, L1.w};

    float acc_n = 0.f, acc_p = 0.f, mx = 0.f;
#pragma unroll
    for (int j = 0; j < 4; ++j) {
        unsigned w3 = (j < 2) ? ux[3] : uy[3];
        unsigned s3w = (j < 2) ? S3x : S3y;
        unsigned s5w = (j < 2) ? S5x : S5y;
        unsigned s7w = (j < 2) ? S7x : S7y;
        const int sh = (j & 1) * 16;
        int S3 = (int)((s3w >> sh) & 0xFFFFu);
        int S5 = (int)((s5w >> sh) & 0xFFFFu);
        int S7 = (int)((s7w >> sh) & 0xFFFFu);
        int lab = (int)((w3 >> sh) & 1u);

        int w = q * 4 + j;
        int cw3 = 1 + min(w, 1) + min(WW - 1 - w, 1);
        int cw5 = 1 + min(w, 2) + min(WW - 1 - w, 2);
        int cw7 = 1 + min(w, 3) + min(WW - 1 - w, 3);

        float fq = (float)(cw3 * chd3 - 2 * S3) * (1.0f / 27.0f)
                 + (float)(cw5 * chd5 - 2 * S5) * (1.0f / 125.0f)
                 + (float)(cw7 * chd7 - 2 * S7) * (1.0f / 343.0f);
        float wm = lab ? (3.0f + fq) : (3.0f - fq);

        float s  = lab ? (l0a[j] - l1a[j]) : (l1a[j] - l0a[j]);
        float nll = fmaxf(s, 0.f) + __logf(1.0f + __expf(-fabsf(s)));

        acc_n += nll;
        acc_p += nll * wm;
        mx = fmaxf(mx, wm);
    }

    // wave reduce (3 waves of 64)
#pragma unroll
    for (int off = 32; off > 0; off >>= 1) {
        acc_n += __shfl_down(acc_n, off);
        acc_p += __shfl_down(acc_p, off);
        mx     = fmaxf(mx, __shfl_down(mx, off));
    }
    __shared__ float s_n[3], s_p[3], s_m[3];
    int wid  = threadIdx.x >> 6;
    int lane = threadIdx.x & 63;
    if (lane == 0) { s_n[wid] = acc_n; s_p[wid] = acc_p; s_m[wid] = mx; }
    __syncthreads();
    if (threadIdx.x == 0) {
        float a = s_n[0] + s_n[1] + s_n[2];
        float p = s_p[0] + s_p[1] + s_p[2];
        float m2 = fmaxf(s_m[0], fmaxf(s_m[1], s_m[2]));
        p_nll[blockIdx.x] = a;
        p_nw[blockIdx.x]  = p;
        p_wm[blockIdx.x]  = m2;
    }
}

// ---------------------------------------------------------------------------
// K4: reduce NBLKS partials -> scalar loss (single block)
// ---------------------------------------------------------------------------
__global__ __launch_bounds__(256) void k_fin(const float* __restrict__ pn,
                                             const float* __restrict__ pw,
                                             const float* __restrict__ pm,
                                             float* __restrict__ out) {
    double s = 0.0, p = 0.0;
    float mx = 0.f;
    for (int t = threadIdx.x; t < NBLKS; t += 256) {
        s += (double)pn[t];
        p += (double)pw[t];
        mx = fmaxf(mx, pm[t]);
    }
#pragma unroll
    for (int off = 32; off > 0; off >>= 1) {
        s  += __shfl_down(s, off);
        p  += __shfl_down(p, off);
        mx  = fmaxf(mx, __shfl_down(mx, off));
    }
    __shared__ double sh_s[4], sh_p[4];
    __shared__ float  sh_m[4];
    int wid  = threadIdx.x >> 6;
    int lane = threadIdx.x & 63;
    if (lane == 0) { sh_s[wid] = s; sh_p[wid] = p; sh_m[wid] = mx; }
    __syncthreads();
    if (threadIdx.x == 0) {
        double S = 0.0, P = 0.0;
        float  M = 0.f;
#pragma unroll
        for (int t = 0; t < 4; ++t) { S += sh_s[t]; P += sh_p[t]; M = fmaxf(M, sh_m[t]); }
        double res = (M > 0.f) ? (S + 2.0 * P / (double)M) : S;
        out[0] = (float)(res / (double)NV);
    }
}

extern "C" void kernel_launch(void* const* d_in, const int* in_sizes, int n_in,
                              void* d_out, int out_size, void* d_ws, size_t ws_size,
                              hipStream_t stream) {
    const float* logits = (const float*)d_in[0];
    const int*   labels = (const int*)d_in[1];
    float*       out    = (float*)d_out;

    char* ws = (char*)d_ws;
    float* p_nll = (float*)ws;                          // NBLKS floats
    float* p_nw  = (float*)(ws + 40960);                // NBLKS floats
    float* p_wm  = (float*)(ws + 81920);                // NBLKS floats
    unsigned short* xs = (unsigned short*)(ws + 131072);
    unsigned short* ys = xs + NV;
    // ws use: 128 KB + 2 * NV * 2 B ~= 28.4 MB; partials fully rewritten
    // every call -> deterministic without memset.

    k_xsum<<<NBLKS, TPB, 0, stream>>>(labels, xs);
    k_ysum<<<NBLKS, TPB, 0, stream>>>(xs, ys);
    k_loss<<<NBLKS, TPB, 0, stream>>>(ys, logits, p_nll, p_nw, p_wm);
    k_fin<<<1, 256, 0, stream>>>(p_nll, p_nw, p_wm, out);
}

// Round 4
// 43.928 us; speedup vs baseline: 23.4399x; 1.1833x over previous
//
#include <hip/hip_runtime.h>

// Problem dims (fixed by reference)
#define BB 2
#define CC 2
#define DD 96
#define HH 192
#define WW 192
static constexpr int NV   = BB * DD * HH * WW;   // 7,077,888 voxels
static constexpr int HW_  = HH * WW;             // 36,864
static constexpr int DHW_ = DD * HW_;            // 3,538,944
static constexpr int ROWS = BB * DD * HH;        // 36,864 W-rows
static constexpr int QPR  = WW / 4;              // 48 int4-quads per row

// k_wh geometry: block = (b,d) slice x 8-quad W-segment, full H in LDS
static constexpr int SEGQ = 8;                   // quads per segment (32 voxels)
static constexpr int NSEG = QPR / SEGQ;          // 6
static constexpr int LSTR = SEGQ + 1;            // LDS row stride (uint2), padded
static constexpr int WHBLKS = BB * DD * NSEG;    // 1152

// k_loss geometry: 192 threads, 8 voxels/thread, 16 rows/block
static constexpr int LBLKS = ROWS / 16;          // 2304

// packed-field masks (2 ushorts per uint32)
#define PM1  0x00010001u
#define PM3  0x00030003u
#define PM7  0x00070007u
#define PMF  0x000F000Fu
#define PM1F 0x001F001Fu
#define PM3F 0x003F003Fu

// ---------------------------------------------------------------------------
// k_wh: fused W-window + H-window sums.
// Stage A: W-sums (k=3,5,7) packed u16 (bit0=lab, b1-2=s3, b3-5=s5, b6-8=s7)
//          into LDS for all 192 rows of this 8-quad segment.
// Stage B: H-sums from LDS -> ys packed u16
//          (bit0=lab, b1-4=t3<=9, b5-9=t5<=25, b10-15=t7<=49).
// ---------------------------------------------------------------------------
__device__ __forceinline__ unsigned ypack(const unsigned* g) {
    unsigned t3 = ((g[2] >> 1) & PM3) + ((g[3] >> 1) & PM3) + ((g[4] >> 1) & PM3);
    unsigned t5 = ((g[1] >> 3) & PM7) + ((g[2] >> 3) & PM7) + ((g[3] >> 3) & PM7)
                + ((g[4] >> 3) & PM7) + ((g[5] >> 3) & PM7);
    unsigned t7 = ((g[0] >> 6) & PM7) + ((g[1] >> 6) & PM7) + ((g[2] >> 6) & PM7)
                + ((g[3] >> 6) & PM7) + ((g[4] >> 6) & PM7) + ((g[5] >> 6) & PM7)
                + ((g[6] >> 6) & PM7);
    return (g[3] & PM1) | (t3 << 1) | (t5 << 5) | (t7 << 10);
}

__global__ __launch_bounds__(256) void k_wh(const int* __restrict__ lab,
                                            unsigned short* __restrict__ ys) {
    __shared__ uint2 lds[HH * LSTR];             // 13,824 B
    int blk  = blockIdx.x;
    int seg  = blk % NSEG;
    int bd   = blk / NSEG;                       // (b*DD + d), 0..191
    int base = bd * HW_;                         // voxel index of (b,d,0,0)
    const int4* l4 = (const int4*)lab;
    int bq = base >> 2;

    // ---- Stage A: W-sums -> LDS -----------------------------------------
    for (int t = threadIdx.x; t < HH * SEGQ; t += 256) {
        int row  = t >> 3;
        int qloc = t & 7;
        int gq   = seg * SEGQ + qloc;
        int qi   = bq + row * QPR + gq;
        int4 cur = l4[qi];
        int4 prv = (gq > 0)       ? l4[qi - 1] : int4{0, 0, 0, 0};
        int4 nxt = (gq < QPR - 1) ? l4[qi + 1] : int4{0, 0, 0, 0};
        int v[12] = {prv.x, prv.y, prv.z, prv.w,
                     cur.x, cur.y, cur.z, cur.w,
                     nxt.x, nxt.y, nxt.z, nxt.w};
        int s7[4], s5[4], s3[4];
        s7[0] = v[1] + v[2] + v[3] + v[4] + v[5] + v[6] + v[7];
#pragma unroll
        for (int j = 0; j < 3; ++j) s7[j + 1] = s7[j] - v[j + 1] + v[j + 8];
#pragma unroll
        for (int j = 0; j < 4; ++j) {
            s5[j] = s7[j] - v[j + 1] - v[j + 7];
            s3[j] = s5[j] - v[j + 2] - v[j + 6];
        }
        unsigned o0 = (unsigned)(v[4] | (s3[0] << 1) | (s5[0] << 3) | (s7[0] << 6));
        unsigned o1 = (unsigned)(v[5] | (s3[1] << 1) | (s5[1] << 3) | (s7[1] << 6));
        unsigned o2 = (unsigned)(v[6] | (s3[2] << 1) | (s5[2] << 3) | (s7[2] << 6));
        unsigned o3 = (unsigned)(v[7] | (s3[3] << 1) | (s5[3] << 3) | (s7[3] << 6));
        uint2 st;
        st.x = o0 | (o1 << 16);
        st.y = o2 | (o3 << 16);
        lds[row * LSTR + qloc] = st;
    }
    __syncthreads();

    // ---- Stage B: H-sums -> ys ------------------------------------------
    for (int t = threadIdx.x; t < HH * SEGQ; t += 256) {
        int row  = t >> 3;
        int qloc = t & 7;
        int gq   = seg * SEGQ + qloc;
        unsigned gx[7], gy[7];
#pragma unroll
        for (int k = 0; k < 7; ++k) {
            int hh = row + k - 3;
            if (hh >= 0 && hh < HH) {
                uint2 u = lds[hh * LSTR + qloc];
                gx[k] = u.x; gy[k] = u.y;
            } else { gx[k] = 0u; gy[k] = 0u; }
        }
        uint2 st;
        st.x = ypack(gx);
        st.y = ypack(gy);
        *(uint2*)(ys + base + row * WW + gq * 4) = st;
    }
}

// ---------------------------------------------------------------------------
// k_loss: D-window SWAR sums -> S3,S5,S7; analytic border counts (interior
// fast path); wm = 3 + sgn*fq; nll = softplus(sgn*(l0-l1)); block partials.
// 192 threads, 8 voxels/thread, 16 rows/block.
// ---------------------------------------------------------------------------
__global__ __launch_bounds__(192) void k_loss(const unsigned short* __restrict__ ys,
                                              const float* __restrict__ logits,
                                              float* __restrict__ p_nll,
                                              float* __restrict__ p_nw,
                                              float* __restrict__ p_wm) {
    int tid  = threadIdx.x;
    int rloc = tid / 24;          // 0..7
    int q8   = tid % 24;          // 8-voxel group within row
    bool interior = (q8 > 0) && (q8 < 23);

    float acc_n = 0.f, acc_p = 0.f, mx = 0.f;

#pragma unroll
    for (int it = 0; it < 2; ++it) {
        int row = blockIdx.x * 16 + it * 8 + rloc;
        int h   = row % HH;
        int rd  = row / HH;
        int d   = rd % DD;
        int b   = rd / DD;
        int i0  = row * WW + q8 * 8;

        unsigned u[7][4];
#pragma unroll
        for (int k = 0; k < 7; ++k) {
            int dd = d + k - 3;
            if (dd >= 0 && dd < DD) {
                uint4 t4 = *(const uint4*)(ys + i0 + (k - 3) * HW_);
                u[k][0] = t4.x; u[k][1] = t4.y; u[k][2] = t4.z; u[k][3] = t4.w;
            } else {
                u[k][0] = 0u; u[k][1] = 0u; u[k][2] = 0u; u[k][3] = 0u;
            }
        }
        unsigned S3[4], S5[4], S7[4];
#pragma unroll
        for (int w = 0; w < 4; ++w) {
            S3[w] = ((u[2][w] >> 1) & PMF) + ((u[3][w] >> 1) & PMF) + ((u[4][w] >> 1) & PMF);
            S5[w] = ((u[1][w] >> 5) & PM1F) + ((u[2][w] >> 5) & PM1F) + ((u[3][w] >> 5) & PM1F)
                  + ((u[4][w] >> 5) & PM1F) + ((u[5][w] >> 5) & PM1F);
            S7[w] = ((u[0][w] >> 10) & PM3F) + ((u[1][w] >> 10) & PM3F) + ((u[2][w] >> 10) & PM3F)
                  + ((u[3][w] >> 10) & PM3F) + ((u[4][w] >> 10) & PM3F) + ((u[5][w] >> 10) & PM3F)
                  + ((u[6][w] >> 10) & PM3F);
        }

        int ch3 = 1 + min(h, 1) + min(HH - 1 - h, 1);
        int ch5 = 1 + min(h, 2) + min(HH - 1 - h, 2);
        int ch7 = 1 + min(h, 3) + min(HH - 1 - h, 3);
        int cd3 = 1 + min(d, 1) + min(DD - 1 - d, 1);
        int cd5 = 1 + min(d, 2) + min(DD - 1 - d, 2);
        int cd7 = 1 + min(d, 3) + min(DD - 1 - d, 3);
        int chd3 = ch3 * cd3, chd5 = ch5 * cd5, chd7 = ch7 * cd7;
        int i3 = 3 * chd3, i5 = 5 * chd5, i7 = 7 * chd7;   // interior counts

        const float* lp = logits + i0 + b * DHW_;
        const float4 A0 = *(const float4*)(lp);
        const float4 A1 = *(const float4*)(lp + 4);
        const float4 B0 = *(const float4*)(lp + DHW_);
        const float4 B1 = *(const float4*)(lp + DHW_ + 4);
        float l0[8] = {A0.x, A0.y, A0.z, A0.w, A1.x, A1.y, A1.z, A1.w};
        float l1[8] = {B0.x, B0.y, B0.z, B0.w, B1.x, B1.y, B1.z, B1.w};

#pragma unroll
        for (int j = 0; j < 8; ++j) {
            const int wd = j >> 1;
            const int sh = (j & 1) * 16;
            int S3j  = (int)((S3[wd] >> sh) & 0xFFFFu);
            int S5j  = (int)((S5[wd] >> sh) & 0xFFFFu);
            int S7j  = (int)((S7[wd] >> sh) & 0xFFFFu);
            int labj = (int)((u[3][wd] >> sh) & 1u);

            int c3 = i3, c5 = i5, c7 = i7;
            if (!interior) {
                int w = q8 * 8 + j;
                int cw3 = 1 + min(w, 1) + min(WW - 1 - w, 1);
                int cw5 = 1 + min(w, 2) + min(WW - 1 - w, 2);
                int cw7 = 1 + min(w, 3) + min(WW - 1 - w, 3);
                c3 = cw3 * chd3; c5 = cw5 * chd5; c7 = cw7 * chd7;
            }
            float fq = (float)(c3 - 2 * S3j) * (1.0f / 27.0f)
                     + (float)(c5 - 2 * S5j) * (1.0f / 125.0f)
                     + (float)(c7 - 2 * S7j) * (1.0f / 343.0f);
            float sgn = labj ? 1.0f : -1.0f;
            float wm  = fmaf(sgn, fq, 3.0f);
            float s   = sgn * (l0[j] - l1[j]);
            float nll = fmaxf(s, 0.f) + __logf(1.0f + __expf(-fabsf(s)));

            acc_n += nll;
            acc_p += nll * wm;
            mx = fmaxf(mx, wm);
        }
    }

    // reduce 3 waves
#pragma unroll
    for (int off = 32; off > 0; off >>= 1) {
        acc_n += __shfl_down(acc_n, off);
        acc_p += __shfl_down(acc_p, off);
        mx     = fmaxf(mx, __shfl_down(mx, off));
    }
    __shared__ float s_n[3], s_p[3], s_m[3];
    int wid  = tid >> 6;
    int lane = tid & 63;
    if (lane == 0) { s_n[wid] = acc_n; s_p[wid] = acc_p; s_m[wid] = mx; }
    __syncthreads();
    if (tid == 0) {
        p_nll[blockIdx.x] = s_n[0] + s_n[1] + s_n[2];
        p_nw[blockIdx.x]  = s_p[0] + s_p[1] + s_p[2];
        p_wm[blockIdx.x]  = fmaxf(s_m[0], fmaxf(s_m[1], s_m[2]));
    }
}

// ---------------------------------------------------------------------------
// k_fin: reduce LBLKS partials -> scalar loss (single block)
// ---------------------------------------------------------------------------
__global__ __launch_bounds__(256) void k_fin(const float* __restrict__ pn,
                                             const float* __restrict__ pw,
                                             const float* __restrict__ pm,
                                             float* __restrict__ out) {
    double s = 0.0, p = 0.0;
    float mx = 0.f;
    for (int t = threadIdx.x; t < LBLKS; t += 256) {
        s += (double)pn[t];
        p += (double)pw[t];
        mx = fmaxf(mx, pm[t]);
    }
#pragma unroll
    for (int off = 32; off > 0; off >>= 1) {
        s  += __shfl_down(s, off);
        p  += __shfl_down(p, off);
        mx  = fmaxf(mx, __shfl_down(mx, off));
    }
    __shared__ double sh_s[4], sh_p[4];
    __shared__ float  sh_m[4];
    int wid  = threadIdx.x >> 6;
    int lane = threadIdx.x & 63;
    if (lane == 0) { sh_s[wid] = s; sh_p[wid] = p; sh_m[wid] = mx; }
    __syncthreads();
    if (threadIdx.x == 0) {
        double S = 0.0, P = 0.0;
        float  M = 0.f;
#pragma unroll
        for (int t = 0; t < 4; ++t) { S += sh_s[t]; P += sh_p[t]; M = fmaxf(M, sh_m[t]); }
        double res = (M > 0.f) ? (S + 2.0 * P / (double)M) : S;
        out[0] = (float)(res / (double)NV);
    }
}

extern "C" void kernel_launch(void* const* d_in, const int* in_sizes, int n_in,
                              void* d_out, int out_size, void* d_ws, size_t ws_size,
                              hipStream_t stream) {
    const float* logits = (const float*)d_in[0];
    const int*   labels = (const int*)d_in[1];
    float*       out    = (float*)d_out;

    char* ws = (char*)d_ws;
    float* p_nll = (float*)ws;                          // LBLKS floats
    float* p_nw  = (float*)(ws + 16384);                // LBLKS floats
    float* p_wm  = (float*)(ws + 32768);                // LBLKS floats
    unsigned short* ys = (unsigned short*)(ws + 65536);
    // ws use: 64 KB + NV*2 B ~= 14.2 MB; all written every call -> no memset.

    k_wh  <<<WHBLKS, 256, 0, stream>>>(labels, ys);
    k_loss<<<LBLKS, 192, 0, stream>>>(ys, logits, p_nll, p_nw, p_wm);
    k_fin <<<1, 256, 0, stream>>>(p_nll, p_nw, p_wm, out);
}